// Round 2
// baseline (644.310 us; speedup 1.0000x reference)
//
#include <hip/hip_runtime.h>

#define TT 2048
#define BB 4
#define DD 1024
#define HH 16
#define HDIM 64
#define MM (TT*BB)   // 8192 rows, row index m = t*BB + b

typedef __attribute__((ext_vector_type(4))) float float4v;
typedef _Float16 half8 __attribute__((ext_vector_type(8)));
typedef _Float16 half4 __attribute__((ext_vector_type(4)));
typedef _Float16 half2v __attribute__((ext_vector_type(2)));

static __device__ __forceinline__ half4 pk4(float a, float b, float c, float d) {
    half2v h0 = __builtin_bit_cast(half2v, __builtin_amdgcn_cvt_pkrtz(a, b));
    half2v h1 = __builtin_bit_cast(half2v, __builtin_amdgcn_cvt_pkrtz(c, d));
    half4 hv; hv[0]=h0[0]; hv[1]=h0[1]; hv[2]=h1[0]; hv[3]=h1[1];
    return hv;
}

// guaranteed single-instruction 2^x (v_exp_f32)
static __device__ __forceinline__ float fexp2(float x) {
    float r; asm("v_exp_f32 %0, %1" : "=v"(r) : "v"(x)); return r;
}

// async global->LDS, 16B per lane; LDS dest wave-uniform base (+lane*16)
#define GLD16(g, l) __builtin_amdgcn_global_load_lds( \
    (const __attribute__((address_space(1))) unsigned int*)(g), \
    (__attribute__((address_space(3))) unsigned int*)(l), 16, 0, 0)

// ---------------------------------------------------------------------------
// Kernel 0: fp32 -> fp16 convert of X (q,k,v) and W (Wq,Wk,Wv,Wo).
// ---------------------------------------------------------------------------
__global__ __launch_bounds__(256) void cvt_f16(
    const float* __restrict__ q, const float* __restrict__ k, const float* __restrict__ v,
    const float* __restrict__ wq, const float* __restrict__ wk, const float* __restrict__ wv,
    const float* __restrict__ wo,
    _Float16* __restrict__ qh, _Float16* __restrict__ kh, _Float16* __restrict__ vh,
    _Float16* __restrict__ wqh, _Float16* __restrict__ wkh, _Float16* __restrict__ wvh,
    _Float16* __restrict__ woh)
{
    const int z = blockIdx.z;
    const float* src; _Float16* dst; int n;
    switch (z) {
        case 0: src=q;  dst=qh;  n=MM*DD/8; break;
        case 1: src=k;  dst=kh;  n=MM*DD/8; break;
        case 2: src=v;  dst=vh;  n=MM*DD/8; break;
        case 3: src=wq; dst=wqh; n=DD*DD/8; break;
        case 4: src=wk; dst=wkh; n=DD*DD/8; break;
        case 5: src=wv; dst=wvh; n=DD*DD/8; break;
        default: src=wo; dst=woh; n=DD*DD/8; break;
    }
    for (int c = blockIdx.x*blockDim.x + threadIdx.x; c < n; c += gridDim.x*blockDim.x) {
        const float4v* s4 = (const float4v*)src + (size_t)c*2;
        float4v a = s4[0], b = s4[1];
        *(half4*)(dst + (size_t)c*8)     = pk4(a[0],a[1],a[2],a[3]);
        *(half4*)(dst + (size_t)c*8 + 4) = pk4(b[0],b[1],b[2],b[3]);
    }
}

// ---------------------------------------------------------------------------
// Kernel 1: QKV projection, pure-fp16 GEMM (m97-structure, global_load_lds).
// Output in plain (T,B,D) row-major = C[m][n] (coalesced epilogue).
// Q output pre-scaled by (1/sqrt(HD))*log2(e) so attn can exp2 directly.
// ---------------------------------------------------------------------------
__global__ __launch_bounds__(256) void qkv_gemm(
    const _Float16* __restrict__ xq, const _Float16* __restrict__ xk, const _Float16* __restrict__ xv,
    const _Float16* __restrict__ wqh, const _Float16* __restrict__ wkh, const _Float16* __restrict__ wvh,
    const float* __restrict__ bq, const float* __restrict__ bk, const float* __restrict__ bv,
    _Float16* __restrict__ dq, _Float16* __restrict__ dk, _Float16* __restrict__ dv)
{
    const int z = blockIdx.z;
    const _Float16* X = (z==0)?xq:((z==1)?xk:xv);
    const _Float16* W = (z==0)?wqh:((z==1)?wkh:wvh);
    const float* Bb   = (z==0)?bq:((z==1)?bk:bv);
    _Float16* Dst     = (z==0)?dq:((z==1)?dk:dv);
    const float osc   = (z==0) ? 0.18033688011112042f : 1.0f;  // (1/8)*log2(e)

    __shared__ __attribute__((aligned(16))) _Float16 As[128*64];
    __shared__ __attribute__((aligned(16))) _Float16 Bs[128*64];

    const int tid=threadIdx.x, lane=tid&63, w=tid>>6;
    const int wm=w>>1, wn=w&1;
    const int m0=blockIdx.y*128, n0=blockIdx.x*128;
    const int lrow=lane&15, lg=lane>>4;

    const _Float16* ga = X + (size_t)(m0 + w*32 + (lane>>3))*DD + (lane&7)*8;
    const _Float16* gb = W + (size_t)(n0 + w*32 + (lane>>3))*DD + (lane&7)*8;
    _Float16* la = As + (w*32)*64;
    _Float16* lb = Bs + (w*32)*64;

    float4v acc[4][4];
    for (int i=0;i<4;i++) for (int j=0;j<4;j++) acc[i][j]=(float4v){0.f,0.f,0.f,0.f};

    for (int k0=0;k0<DD;k0+=64) {
        __syncthreads();
        #pragma unroll
        for (int s=0;s<4;s++) GLD16(ga + (size_t)s*8*DD + k0, la + s*8*64);
        #pragma unroll
        for (int s=0;s<4;s++) GLD16(gb + (size_t)s*8*DD + k0, lb + s*8*64);
        __syncthreads();
        #pragma unroll
        for (int kc=0;kc<2;kc++) {
            half8 a[4], b[4];
            #pragma unroll
            for (int i=0;i<4;i++) a[i] = *(const half8*)&As[(wm*64+i*16+lrow)*64 + kc*32 + lg*8];
            #pragma unroll
            for (int j=0;j<4;j++) b[j] = *(const half8*)&Bs[(wn*64+j*16+lrow)*64 + kc*32 + lg*8];
            #pragma unroll
            for (int i=0;i<4;i++)
            #pragma unroll
            for (int j=0;j<4;j++)
                acc[i][j] = __builtin_amdgcn_mfma_f32_16x16x32_f16(a[i], b[j], acc[i][j],0,0,0);
        }
    }
    // epilogue: + bias, (Q only) * exp2-scale, coalesced (T,B,D) = [m][n]
    #pragma unroll
    for (int j=0;j<4;j++) {
        int n = n0 + wn*64 + j*16 + lrow;
        float bias = Bb[n];
        #pragma unroll
        for (int i=0;i<4;i++)
        #pragma unroll
        for (int r=0;r<4;r++) {
            int m = m0 + wm*64 + i*16 + lg*4 + r;
            Dst[(size_t)m*DD + n] = (_Float16)((acc[i][j][r] + bias)*osc);
        }
    }
}

// ---------------------------------------------------------------------------
// Kernel 1b: V (T,B,D) -> V^T (B,H,HD,T). 4x4-cell register transpose.
// ---------------------------------------------------------------------------
__global__ __launch_bounds__(256) void v_transpose(
    const _Float16* __restrict__ Vh, _Float16* __restrict__ VbT)
{
    const int tile = blockIdx.x;            // t-tile 0..31
    const int bh   = blockIdx.y;            // 0..63
    const int b = bh >> 4, h = bh & 15;
    const int tid = threadIdx.x, tg = tid & 15, hg = tid >> 4;
    const int t0 = tile*64;

    half4 rv[4];
    #pragma unroll
    for (int r=0;r<4;r++)
        rv[r] = *(const half4*)(Vh + ((size_t)(t0 + tg*4 + r)*BB + b)*DD + h*HDIM + hg*4);
    #pragma unroll
    for (int c=0;c<4;c++) {
        half4 tv; tv[0]=rv[0][c]; tv[1]=rv[1][c]; tv[2]=rv[2][c]; tv[3]=rv[3][c];
        *(half4*)(VbT + ((size_t)bh*HDIM + hg*4 + c)*TT + t0 + tg*4) = tv;
    }
}

// ---------------------------------------------------------------------------
// Kernel 2: flash-style attention, fp16, max-free softmax.
// ZERO LDS / ZERO barriers. Swapped QK^T (mfma(K,Q)) puts each lane's P
// values at t = j*16 + lg*4 + r  == exactly the K=16 MFMA fragment layout,
// so PV consumes P directly from registers via mfma_f32_16x16x16f16.
// V^T fragments come straight from the pre-transposed global buffer.
// Grid 1D with id%64 = bh -> same-bh blocks share an XCD's L2 (id%8=bh%8).
// ---------------------------------------------------------------------------
__global__ __launch_bounds__(256, 4) void attn(
    const _Float16* __restrict__ Qg, const _Float16* __restrict__ Kg,
    const _Float16* __restrict__ VT, _Float16* __restrict__ Ctx)
{
    const int id = blockIdx.x;
    const int bh = id & 63, qt = id >> 6;
    const int b = bh >> 4, h = bh & 15;
    const int tid = threadIdx.x, lane = tid & 63, w = tid >> 6;
    const int lrow = lane & 15, lg = lane >> 4;

    // (T,B,D) addressing: addr(t, col) = (t*BB + b)*DD + h*HDIM + col
    const size_t TROW = (size_t)BB*DD;   // halfs per t-step
    const _Float16* Qrow = Qg + ((size_t)(qt*128 + w*32 + lrow)*BB + b)*DD + h*HDIM;
    const _Float16* Krow = Kg + ((size_t)lrow*BB + b)*DD + h*HDIM;
    const _Float16* Vrow = VT + ((size_t)bh*HDIM + lrow)*TT;   // [hd=...+lrow][t]

    // Q fragments: q rows w*32 + i*16 + lrow, hd = kc*32 + lg*8
    half8 qf[2][2];
    #pragma unroll
    for (int i=0;i<2;i++)
    #pragma unroll
    for (int kc=0;kc<2;kc++)
        qf[i][kc] = *(const half8*)(Qrow + (size_t)i*16*TROW + kc*32 + lg*8);

    float4v oacc[2][4];   // [i][jo]: O^T: hd = jo*16+lg*4+r, q = i*16+lrow
    for (int i=0;i<2;i++) for (int j=0;j<4;j++) oacc[i][j]=(float4v){0.f,0.f,0.f,0.f};
    float lsum[2] = {0.f, 0.f};

    for (int kt = 0; kt < 32; kt++) {
        // ---- S^T = K Q^T (swapped): st[j][i][r] = S[q=i*16+lrow][t=j*16+lg*4+r]
        float4v st[4][2];
        #pragma unroll
        for (int j=0;j<4;j++) for (int i=0;i<2;i++) st[j][i]=(float4v){0.f,0.f,0.f,0.f};
        #pragma unroll
        for (int kc=0;kc<2;kc++) {
            half8 kf[4];
            #pragma unroll
            for (int j=0;j<4;j++)
                kf[j] = *(const half8*)(Krow + (size_t)(kt*64 + j*16)*TROW + kc*32 + lg*8);
            __builtin_amdgcn_s_setprio(1);
            #pragma unroll
            for (int j=0;j<4;j++)
            #pragma unroll
            for (int i=0;i<2;i++)
                st[j][i] = __builtin_amdgcn_mfma_f32_16x16x32_f16(kf[j], qf[i][kc], st[j][i],0,0,0);
            __builtin_amdgcn_s_setprio(0);
        }

        // ---- per-j: exp + pack + PV (K=16 MFMA, P stays in registers)
        // V^T frag: vf[jo] = V^T[hd=jo*16+lrow][t = kt*64 + j*16 + lg*4 .. +3]
        half4 vfc[4], vfn[4];
        #pragma unroll
        for (int jo=0;jo<4;jo++)
            vfc[jo] = *(const half4*)(Vrow + (size_t)jo*16*TT + kt*64 + lg*4);
        #pragma unroll
        for (int j=0;j<4;j++) {
            if (j < 3) {
                #pragma unroll
                for (int jo=0;jo<4;jo++)
                    vfn[jo] = *(const half4*)(Vrow + (size_t)jo*16*TT + kt*64 + (j+1)*16 + lg*4);
            }
            half4 pa[2];
            #pragma unroll
            for (int i=0;i<2;i++) {
                float p0 = fexp2(st[j][i][0]);
                float p1 = fexp2(st[j][i][1]);
                float p2 = fexp2(st[j][i][2]);
                float p3 = fexp2(st[j][i][3]);
                lsum[i] += (p0+p1)+(p2+p3);
                pa[i] = pk4(p0,p1,p2,p3);
            }
            __builtin_amdgcn_s_setprio(1);
            #pragma unroll
            for (int i=0;i<2;i++)
            #pragma unroll
            for (int jo=0;jo<4;jo++)
                oacc[i][jo] = __builtin_amdgcn_mfma_f32_16x16x16f16(vfc[jo], pa[i], oacc[i][jo],0,0,0);
            __builtin_amdgcn_s_setprio(0);
            #pragma unroll
            for (int jo=0;jo<4;jo++) vfc[jo] = vfn[jo];
        }
    }

    // row sums: lane covers t ≡ lg*4+r (mod 16); reduce over the 4 lg groups
    #pragma unroll
    for (int i=0;i<2;i++) {
        float s = lsum[i];
        s += __shfl_xor(s, 16, 64);
        s += __shfl_xor(s, 32, 64);
        lsum[i] = s;
    }

    // finalize: O^T/l -> ctx fp16 (T,B,D); per (i,jo): 4 consecutive hd -> 8B store
    #pragma unroll
    for (int i=0;i<2;i++) {
        float inv = 1.f / lsum[i];
        int t = qt*128 + w*32 + i*16 + lrow;
        _Float16* crow = Ctx + ((size_t)t*BB + b)*DD + h*HDIM;
        #pragma unroll
        for (int jo=0;jo<4;jo++) {
            *(half4*)(crow + jo*16 + lg*4) =
                pk4(oacc[i][jo][0]*inv, oacc[i][jo][1]*inv,
                    oacc[i][jo][2]*inv, oacc[i][jo][3]*inv);
        }
    }
}

// ---------------------------------------------------------------------------
// Kernel 3: out = (ctx @ Wo.T + bo) * time_decay, fp16 GEMM, fp32 out.
// ---------------------------------------------------------------------------
__global__ __launch_bounds__(256) void out_gemm(
    const _Float16* __restrict__ Cx, const _Float16* __restrict__ Woh,
    const float* __restrict__ bo, const float* __restrict__ td,
    float* __restrict__ Out)
{
    __shared__ __attribute__((aligned(16))) _Float16 As[128*64];
    __shared__ __attribute__((aligned(16))) _Float16 Bs[128*64];

    const int tid=threadIdx.x, lane=tid&63, w=tid>>6;
    const int wm=w>>1, wn=w&1;
    const int m0=blockIdx.y*128, n0=blockIdx.x*128;
    const int lrow=lane&15, lg=lane>>4;

    const _Float16* ga = Cx  + (size_t)(m0 + w*32 + (lane>>3))*DD + (lane&7)*8;
    const _Float16* gb = Woh + (size_t)(n0 + w*32 + (lane>>3))*DD + (lane&7)*8;
    _Float16* la = As + (w*32)*64;
    _Float16* lb = Bs + (w*32)*64;

    float4v acc[4][4];
    for (int i=0;i<4;i++) for (int j=0;j<4;j++) acc[i][j]=(float4v){0.f,0.f,0.f,0.f};

    for (int k0=0;k0<DD;k0+=64) {
        __syncthreads();
        #pragma unroll
        for (int s=0;s<4;s++) GLD16(ga + (size_t)s*8*DD + k0, la + s*8*64);
        #pragma unroll
        for (int s=0;s<4;s++) GLD16(gb + (size_t)s*8*DD + k0, lb + s*8*64);
        __syncthreads();
        #pragma unroll
        for (int kc=0;kc<2;kc++) {
            half8 a[4], b[4];
            #pragma unroll
            for (int i=0;i<4;i++) a[i] = *(const half8*)&As[(wm*64+i*16+lrow)*64 + kc*32 + lg*8];
            #pragma unroll
            for (int j=0;j<4;j++) b[j] = *(const half8*)&Bs[(wn*64+j*16+lrow)*64 + kc*32 + lg*8];
            #pragma unroll
            for (int i=0;i<4;i++)
            #pragma unroll
            for (int j=0;j<4;j++)
                acc[i][j] = __builtin_amdgcn_mfma_f32_16x16x32_f16(a[i], b[j], acc[i][j],0,0,0);
        }
    }
    #pragma unroll
    for (int j=0;j<4;j++) {
        int n = n0 + wn*64 + j*16 + lrow;
        float bias = bo[n];
        #pragma unroll
        for (int i=0;i<4;i++)
        #pragma unroll
        for (int r=0;r<4;r++) {
            int m = m0 + wm*64 + i*16 + lg*4 + r;
            size_t off = (size_t)m*DD + n;
            Out[off] = (acc[i][j][r] + bias) * td[off];
        }
    }
}

// ---------------------------------------------------------------------------
extern "C" void kernel_launch(void* const* d_in, const int* in_sizes, int n_in,
                              void* d_out, int out_size, void* d_ws, size_t ws_size,
                              hipStream_t stream) {
    const float* q  = (const float*)d_in[0];
    const float* k  = (const float*)d_in[1];
    const float* v  = (const float*)d_in[2];
    const float* td = (const float*)d_in[3];
    const float* Wq = (const float*)d_in[4];
    const float* bq = (const float*)d_in[5];
    const float* Wk = (const float*)d_in[6];
    const float* bk = (const float*)d_in[7];
    const float* Wv = (const float*)d_in[8];
    const float* bv = (const float*)d_in[9];
    const float* Wo = (const float*)d_in[10];
    const float* bo = (const float*)d_in[11];
    float* out = (float*)d_out;

    // workspace (104 MB):
    //  [qh 16M][kh 16M][vh 16M][wqh 2M][wkh 2M][wvh 2M][woh 2M][Qb 16M][Kb 16M][Vb 16M]
    //  VbT aliases vh (dead after qkv_gemm); Cx aliases qh (dead after qkv_gemm).
    _Float16* qh  = (_Float16*)d_ws;
    _Float16* kh  = qh  + (size_t)MM*DD;
    _Float16* vh  = kh  + (size_t)MM*DD;
    _Float16* wqh = vh  + (size_t)MM*DD;
    _Float16* wkh = wqh + (size_t)DD*DD;
    _Float16* wvh = wkh + (size_t)DD*DD;
    _Float16* woh = wvh + (size_t)DD*DD;
    _Float16* Qb  = woh + (size_t)DD*DD;
    _Float16* Kb  = Qb  + (size_t)MM*DD;
    _Float16* Vb  = Kb  + (size_t)MM*DD;
    _Float16* VbT = vh;   // alias: vh dead after qkv_gemm
    _Float16* Cx  = qh;   // alias: qh dead after qkv_gemm

    cvt_f16    <<<dim3(2048,1,7), 256, 0, stream>>>(q,k,v, Wq,Wk,Wv,Wo, qh,kh,vh, wqh,wkh,wvh,woh);
    qkv_gemm   <<<dim3(8,64,3),   256, 0, stream>>>(qh,kh,vh, wqh,wkh,wvh, bq,bk,bv, Qb,Kb,Vb);
    v_transpose<<<dim3(32,64),    256, 0, stream>>>(Vb, VbT);
    attn       <<<dim3(1024),     256, 0, stream>>>(Qb, Kb, VbT, Cx);
    out_gemm   <<<dim3(8,64),     256, 0, stream>>>(Cx, woh, bo, td, out);
}

// Round 3
// 394.121 us; speedup vs baseline: 1.6348x; 1.6348x over previous
//
#include <hip/hip_runtime.h>

#define TT 2048
#define BB 4
#define DD 1024
#define HH 16
#define HDIM 64
#define MM (TT*BB)   // 8192 rows, row index m = t*BB + b

typedef __attribute__((ext_vector_type(4))) float float4v;
typedef _Float16 half8 __attribute__((ext_vector_type(8)));
typedef _Float16 half4 __attribute__((ext_vector_type(4)));
typedef _Float16 half2v __attribute__((ext_vector_type(2)));

static __device__ __forceinline__ half4 pk4(float a, float b, float c, float d) {
    half2v h0 = __builtin_bit_cast(half2v, __builtin_amdgcn_cvt_pkrtz(a, b));
    half2v h1 = __builtin_bit_cast(half2v, __builtin_amdgcn_cvt_pkrtz(c, d));
    half4 hv; hv[0]=h0[0]; hv[1]=h0[1]; hv[2]=h1[0]; hv[3]=h1[1];
    return hv;
}

// guaranteed single-instruction 2^x (v_exp_f32)
static __device__ __forceinline__ float fexp2(float x) {
    float r; asm("v_exp_f32 %0, %1" : "=v"(r) : "v"(x)); return r;
}

// async global->LDS, 16B per lane; LDS dest wave-uniform base (+lane*16B)
#define GLD16(g, l) __builtin_amdgcn_global_load_lds( \
    (const __attribute__((address_space(1))) unsigned int*)(g), \
    (__attribute__((address_space(3))) unsigned int*)(l), 16, 0, 0)

// ---------------------------------------------------------------------------
// Kernel 0: fp32 -> fp16 convert of X (q,k,v) and W (Wq,Wk,Wv,Wo).
// ---------------------------------------------------------------------------
__global__ __launch_bounds__(256) void cvt_f16(
    const float* __restrict__ q, const float* __restrict__ k, const float* __restrict__ v,
    const float* __restrict__ wq, const float* __restrict__ wk, const float* __restrict__ wv,
    const float* __restrict__ wo,
    _Float16* __restrict__ qh, _Float16* __restrict__ kh, _Float16* __restrict__ vh,
    _Float16* __restrict__ wqh, _Float16* __restrict__ wkh, _Float16* __restrict__ wvh,
    _Float16* __restrict__ woh)
{
    const int z = blockIdx.z;
    const float* src; _Float16* dst; int n;
    switch (z) {
        case 0: src=q;  dst=qh;  n=MM*DD/8; break;
        case 1: src=k;  dst=kh;  n=MM*DD/8; break;
        case 2: src=v;  dst=vh;  n=MM*DD/8; break;
        case 3: src=wq; dst=wqh; n=DD*DD/8; break;
        case 4: src=wk; dst=wkh; n=DD*DD/8; break;
        case 5: src=wv; dst=wvh; n=DD*DD/8; break;
        default: src=wo; dst=woh; n=DD*DD/8; break;
    }
    for (int c = blockIdx.x*blockDim.x + threadIdx.x; c < n; c += gridDim.x*blockDim.x) {
        const float4v* s4 = (const float4v*)src + (size_t)c*2;
        float4v a = s4[0], b = s4[1];
        *(half4*)(dst + (size_t)c*8)     = pk4(a[0],a[1],a[2],a[3]);
        *(half4*)(dst + (size_t)c*8 + 4) = pk4(b[0],b[1],b[2],b[3]);
    }
}

// ---------------------------------------------------------------------------
// Kernel 1: QKV projection, pure-fp16 GEMM (m97-structure, global_load_lds).
// Output fp16 scattered to (B,H,T,HD) so attn K/Q tiles are contiguous.
// Q output pre-scaled by (1/sqrt(HD))*log2(e) so attn can exp2 directly.
// ---------------------------------------------------------------------------
__global__ __launch_bounds__(256) void qkv_gemm(
    const _Float16* __restrict__ xq, const _Float16* __restrict__ xk, const _Float16* __restrict__ xv,
    const _Float16* __restrict__ wqh, const _Float16* __restrict__ wkh, const _Float16* __restrict__ wvh,
    const float* __restrict__ bq, const float* __restrict__ bk, const float* __restrict__ bv,
    _Float16* __restrict__ dq, _Float16* __restrict__ dk, _Float16* __restrict__ dv)
{
    const int z = blockIdx.z;
    const _Float16* X = (z==0)?xq:((z==1)?xk:xv);
    const _Float16* W = (z==0)?wqh:((z==1)?wkh:wvh);
    const float* Bb   = (z==0)?bq:((z==1)?bk:bv);
    _Float16* Dst     = (z==0)?dq:((z==1)?dk:dv);
    const float osc   = (z==0) ? 0.18033688011112042f : 1.0f;  // (1/8)*log2(e)

    __shared__ __attribute__((aligned(16))) _Float16 As[128*64];
    __shared__ __attribute__((aligned(16))) _Float16 Bs[128*64];

    const int tid=threadIdx.x, lane=tid&63, w=tid>>6;
    const int wm=w>>1, wn=w&1;
    const int m0=blockIdx.y*128, n0=blockIdx.x*128;
    const int lrow=lane&15, lg=lane>>4;

    const _Float16* ga = X + (size_t)(m0 + w*32 + (lane>>3))*DD + (lane&7)*8;
    const _Float16* gb = W + (size_t)(n0 + w*32 + (lane>>3))*DD + (lane&7)*8;
    _Float16* la = As + (w*32)*64;
    _Float16* lb = Bs + (w*32)*64;

    float4v acc[4][4];
    for (int i=0;i<4;i++) for (int j=0;j<4;j++) acc[i][j]=(float4v){0.f,0.f,0.f,0.f};

    for (int k0=0;k0<DD;k0+=64) {
        __syncthreads();
        #pragma unroll
        for (int s=0;s<4;s++) GLD16(ga + (size_t)s*8*DD + k0, la + s*8*64);
        #pragma unroll
        for (int s=0;s<4;s++) GLD16(gb + (size_t)s*8*DD + k0, lb + s*8*64);
        __syncthreads();
        #pragma unroll
        for (int kc=0;kc<2;kc++) {
            half8 a[4], b[4];
            #pragma unroll
            for (int i=0;i<4;i++) a[i] = *(const half8*)&As[(wm*64+i*16+lrow)*64 + kc*32 + lg*8];
            #pragma unroll
            for (int j=0;j<4;j++) b[j] = *(const half8*)&Bs[(wn*64+j*16+lrow)*64 + kc*32 + lg*8];
            #pragma unroll
            for (int i=0;i<4;i++)
            #pragma unroll
            for (int j=0;j<4;j++)
                acc[i][j] = __builtin_amdgcn_mfma_f32_16x16x32_f16(a[i], b[j], acc[i][j],0,0,0);
        }
    }
    // epilogue: + bias, (Q only) exp2-scale, scatter to (B,H,T,HD)
    #pragma unroll
    for (int j=0;j<4;j++) {
        int n = n0 + wn*64 + j*16 + lrow;
        float bias = Bb[n];
        int h = n >> 6, hd = n & 63;
        #pragma unroll
        for (int i=0;i<4;i++)
        #pragma unroll
        for (int r=0;r<4;r++) {
            int m = m0 + wm*64 + i*16 + lg*4 + r;
            int t = m >> 2, b = m & 3;
            Dst[((size_t)(b*HH + h)*TT + t)*HDIM + hd] = (_Float16)((acc[i][j][r] + bias)*osc);
        }
    }
}

// ---------------------------------------------------------------------------
// Kernel 1b: V (B,H,T,HD) -> V^T (B,H,HD,T). 4x4-cell register transpose.
// ---------------------------------------------------------------------------
__global__ __launch_bounds__(256) void v_transpose(
    const _Float16* __restrict__ Vb, _Float16* __restrict__ VbT)
{
    const int tile = blockIdx.x;            // t-tile 0..31
    const int bh   = blockIdx.y;            // 0..63
    const int tid = threadIdx.x, tg = tid & 15, hg = tid >> 4;
    const int t0 = tile*64;

    half4 rv[4];
    #pragma unroll
    for (int r=0;r<4;r++)
        rv[r] = *(const half4*)(Vb + ((size_t)bh*TT + t0 + tg*4 + r)*HDIM + hg*4);
    #pragma unroll
    for (int c=0;c<4;c++) {
        half4 tv; tv[0]=rv[0][c]; tv[1]=rv[1][c]; tv[2]=rv[2][c]; tv[3]=rv[3][c];
        *(half4*)(VbT + ((size_t)bh*HDIM + hg*4 + c)*TT + t0 + tg*4) = tv;
    }
}

// ---------------------------------------------------------------------------
// Kernel 2: flash-style attention, fp16, max-free softmax.
// Round-2 compute structure (swapped QK^T, P in registers, x16 PV MFMA)
// + LDS-staged K and V^T tiles (global_load_lds, double-buffered, 1 barrier
// per kt). LDS linear dest + XOR-swizzled SOURCE (col ^= (row&7)<<3 halfs):
// ds_read_b128/b64 land at the bank floor. LDS 32 KB -> 4 blocks/CU.
// Grid 1D, id%64 = bh -> same-bh blocks share an XCD's L2.
// ---------------------------------------------------------------------------
__global__ __launch_bounds__(256, 4) void attn(
    const _Float16* __restrict__ Qg, const _Float16* __restrict__ Kg,
    const _Float16* __restrict__ VT, _Float16* __restrict__ Ctx)
{
    __shared__ __attribute__((aligned(16))) _Float16 Kt[2][64*64];
    __shared__ __attribute__((aligned(16))) _Float16 Vs[2][64*64];

    const int id = blockIdx.x;
    const int bh = id & 63, qt = id >> 6;
    const int b = bh >> 4, h = bh & 15;
    const int tid = threadIdx.x, lane = tid & 63, w = tid >> 6;
    const int lrow = lane & 15, lg = lane >> 4;

    const _Float16* Qb  = Qg + ((size_t)bh*TT + qt*128)*HDIM;
    const _Float16* Kb  = Kg + (size_t)bh*TT*HDIM;      // [t][hd], rows 128B
    const _Float16* Vtb = VT + (size_t)bh*HDIM*TT;      // [hd][t], rows 4KB

    // staging geometry: wave w stages rows w*16+s*8+(lane>>3), s=0..1, of each
    // tile; per-lane source col pre-swizzled so LDS[r][q] = G[r][q ^ ((r&7)<<3)]
    const int srow = w*16 + (lane>>3);                  // + s*8
    const int scol = ((lane&7) ^ (lane>>3))*8;          // halfs

    // Q fragments: q rows w*32 + i*16 + lrow, hd = kc*32 + lg*8 (contiguous)
    half8 qf[2][2];
    #pragma unroll
    for (int i=0;i<2;i++)
    #pragma unroll
    for (int kc=0;kc<2;kc++)
        qf[i][kc] = *(const half8*)(Qb + (size_t)(w*32 + i*16 + lrow)*HDIM + kc*32 + lg*8);

    float4v oacc[2][4];   // [i][jo]: O^T: hd = jo*16+lg*4+r, q = i*16+lrow
    for (int i=0;i<2;i++) for (int j=0;j<4;j++) oacc[i][j]=(float4v){0.f,0.f,0.f,0.f};
    float lsum[2] = {0.f, 0.f};

    // prologue: stage tile 0 into buffer 0
    #pragma unroll
    for (int s=0;s<2;s++) {
        GLD16(Kb  + (size_t)(srow + s*8)*HDIM + scol,        &Kt[0][(w*16 + s*8)*64]);
        GLD16(Vtb + (size_t)(srow + s*8)*TT   + scol,        &Vs[0][(w*16 + s*8)*64]);
    }
    __syncthreads();

    const int swz = (lrow & 7) << 3;   // read-side XOR (halfs)

    for (int kt = 0; kt < 32; kt++) {
        const int cb = kt & 1, nb = cb ^ 1;

        // issue NEXT tile's async loads first (land during this iter's compute)
        if (kt < 31) {
            #pragma unroll
            for (int s=0;s<2;s++) {
                GLD16(Kb  + (size_t)((kt+1)*64 + srow + s*8)*HDIM + scol, &Kt[nb][(w*16 + s*8)*64]);
                GLD16(Vtb + (size_t)(srow + s*8)*TT + (kt+1)*64 + scol,   &Vs[nb][(w*16 + s*8)*64]);
            }
        }

        // ---- S^T = K Q^T (swapped): st[j][i][r] = S[q=i*16+lrow][t=j*16+lg*4+r]
        float4v st[4][2];
        #pragma unroll
        for (int j=0;j<4;j++) for (int i=0;i<2;i++) st[j][i]=(float4v){0.f,0.f,0.f,0.f};
        #pragma unroll
        for (int kc=0;kc<2;kc++) {
            half8 kf[4];
            #pragma unroll
            for (int j=0;j<4;j++)
                kf[j] = *(const half8*)&Kt[cb][(j*16 + lrow)*64 + ((kc*32 + lg*8) ^ swz)];
            __builtin_amdgcn_s_setprio(1);
            #pragma unroll
            for (int j=0;j<4;j++)
            #pragma unroll
            for (int i=0;i<2;i++)
                st[j][i] = __builtin_amdgcn_mfma_f32_16x16x32_f16(kf[j], qf[i][kc], st[j][i],0,0,0);
            __builtin_amdgcn_s_setprio(0);
        }

        // ---- per-j: exp + pack + PV (K=16 MFMA, P stays in registers)
        #pragma unroll
        for (int j=0;j<4;j++) {
            half4 pa[2];
            #pragma unroll
            for (int i=0;i<2;i++) {
                float p0 = fexp2(st[j][i][0]);
                float p1 = fexp2(st[j][i][1]);
                float p2 = fexp2(st[j][i][2]);
                float p3 = fexp2(st[j][i][3]);
                lsum[i] += (p0+p1)+(p2+p3);
                pa[i] = pk4(p0,p1,p2,p3);
            }
            half4 vf[4];
            #pragma unroll
            for (int jo=0;jo<4;jo++)
                vf[jo] = *(const half4*)&Vs[cb][(jo*16 + lrow)*64 + ((j*16 + lg*4) ^ swz)];
            __builtin_amdgcn_s_setprio(1);
            #pragma unroll
            for (int i=0;i<2;i++)
            #pragma unroll
            for (int jo=0;jo<4;jo++)
                oacc[i][jo] = __builtin_amdgcn_mfma_f32_16x16x16f16(vf[jo], pa[i], oacc[i][jo],0,0,0);
            __builtin_amdgcn_s_setprio(0);
        }

        __syncthreads();   // cur-buffer reads done by all waves; next-tile loads drained
    }

    // row sums: lane covers t ≡ lg*4+r (mod 16); reduce over the 4 lg groups
    #pragma unroll
    for (int i=0;i<2;i++) {
        float s = lsum[i];
        s += __shfl_xor(s, 16, 64);
        s += __shfl_xor(s, 32, 64);
        lsum[i] = s;
    }

    // finalize: O^T/l -> ctx fp16 (T,B,D); per (i,jo): 4 consecutive hd -> 8B store
    #pragma unroll
    for (int i=0;i<2;i++) {
        float inv = 1.f / lsum[i];
        int t = qt*128 + w*32 + i*16 + lrow;
        _Float16* crow = Ctx + ((size_t)t*BB + b)*DD + h*HDIM;
        #pragma unroll
        for (int jo=0;jo<4;jo++) {
            *(half4*)(crow + jo*16 + lg*4) =
                pk4(oacc[i][jo][0]*inv, oacc[i][jo][1]*inv,
                    oacc[i][jo][2]*inv, oacc[i][jo][3]*inv);
        }
    }
}

// ---------------------------------------------------------------------------
// Kernel 3: out = (ctx @ Wo.T + bo) * time_decay, fp16 GEMM, fp32 out.
// ---------------------------------------------------------------------------
__global__ __launch_bounds__(256) void out_gemm(
    const _Float16* __restrict__ Cx, const _Float16* __restrict__ Woh,
    const float* __restrict__ bo, const float* __restrict__ td,
    float* __restrict__ Out)
{
    __shared__ __attribute__((aligned(16))) _Float16 As[128*64];
    __shared__ __attribute__((aligned(16))) _Float16 Bs[128*64];

    const int tid=threadIdx.x, lane=tid&63, w=tid>>6;
    const int wm=w>>1, wn=w&1;
    const int m0=blockIdx.y*128, n0=blockIdx.x*128;
    const int lrow=lane&15, lg=lane>>4;

    const _Float16* ga = Cx  + (size_t)(m0 + w*32 + (lane>>3))*DD + (lane&7)*8;
    const _Float16* gb = Woh + (size_t)(n0 + w*32 + (lane>>3))*DD + (lane&7)*8;
    _Float16* la = As + (w*32)*64;
    _Float16* lb = Bs + (w*32)*64;

    float4v acc[4][4];
    for (int i=0;i<4;i++) for (int j=0;j<4;j++) acc[i][j]=(float4v){0.f,0.f,0.f,0.f};

    for (int k0=0;k0<DD;k0+=64) {
        __syncthreads();
        #pragma unroll
        for (int s=0;s<4;s++) GLD16(ga + (size_t)s*8*DD + k0, la + s*8*64);
        #pragma unroll
        for (int s=0;s<4;s++) GLD16(gb + (size_t)s*8*DD + k0, lb + s*8*64);
        __syncthreads();
        #pragma unroll
        for (int kc=0;kc<2;kc++) {
            half8 a[4], b[4];
            #pragma unroll
            for (int i=0;i<4;i++) a[i] = *(const half8*)&As[(wm*64+i*16+lrow)*64 + kc*32 + lg*8];
            #pragma unroll
            for (int j=0;j<4;j++) b[j] = *(const half8*)&Bs[(wn*64+j*16+lrow)*64 + kc*32 + lg*8];
            #pragma unroll
            for (int i=0;i<4;i++)
            #pragma unroll
            for (int j=0;j<4;j++)
                acc[i][j] = __builtin_amdgcn_mfma_f32_16x16x32_f16(a[i], b[j], acc[i][j],0,0,0);
        }
    }
    #pragma unroll
    for (int j=0;j<4;j++) {
        int n = n0 + wn*64 + j*16 + lrow;
        float bias = bo[n];
        #pragma unroll
        for (int i=0;i<4;i++)
        #pragma unroll
        for (int r=0;r<4;r++) {
            int m = m0 + wm*64 + i*16 + lg*4 + r;
            size_t off = (size_t)m*DD + n;
            Out[off] = (acc[i][j][r] + bias) * td[off];
        }
    }
}

// ---------------------------------------------------------------------------
extern "C" void kernel_launch(void* const* d_in, const int* in_sizes, int n_in,
                              void* d_out, int out_size, void* d_ws, size_t ws_size,
                              hipStream_t stream) {
    const float* q  = (const float*)d_in[0];
    const float* k  = (const float*)d_in[1];
    const float* v  = (const float*)d_in[2];
    const float* td = (const float*)d_in[3];
    const float* Wq = (const float*)d_in[4];
    const float* bq = (const float*)d_in[5];
    const float* Wk = (const float*)d_in[6];
    const float* bk = (const float*)d_in[7];
    const float* Wv = (const float*)d_in[8];
    const float* bv = (const float*)d_in[9];
    const float* Wo = (const float*)d_in[10];
    const float* bo = (const float*)d_in[11];
    float* out = (float*)d_out;

    // workspace (104 MB):
    //  [qh 16M][kh 16M][vh 16M][wqh 2M][wkh 2M][wvh 2M][woh 2M][Qb 16M][Kb 16M][Vb 16M]
    //  VbT aliases vh (dead after qkv_gemm); Cx aliases qh (dead after qkv_gemm).
    _Float16* qh  = (_Float16*)d_ws;
    _Float16* kh  = qh  + (size_t)MM*DD;
    _Float16* vh  = kh  + (size_t)MM*DD;
    _Float16* wqh = vh  + (size_t)MM*DD;
    _Float16* wkh = wqh + (size_t)DD*DD;
    _Float16* wvh = wkh + (size_t)DD*DD;
    _Float16* woh = wvh + (size_t)DD*DD;
    _Float16* Qb  = woh + (size_t)DD*DD;
    _Float16* Kb  = Qb  + (size_t)MM*DD;
    _Float16* Vb  = Kb  + (size_t)MM*DD;
    _Float16* VbT = vh;   // alias: vh dead after qkv_gemm
    _Float16* Cx  = qh;   // alias: qh dead after qkv_gemm

    cvt_f16    <<<dim3(2048,1,7), 256, 0, stream>>>(q,k,v, Wq,Wk,Wv,Wo, qh,kh,vh, wqh,wkh,wvh,woh);
    qkv_gemm   <<<dim3(8,64,3),   256, 0, stream>>>(qh,kh,vh, wqh,wkh,wvh, bq,bk,bv, Qb,Kb,Vb);
    v_transpose<<<dim3(32,64),    256, 0, stream>>>(Vb, VbT);
    attn       <<<dim3(1024),     256, 0, stream>>>(Qb, Kb, VbT, Cx);
    out_gemm   <<<dim3(8,64),     256, 0, stream>>>(Cx, woh, bo, td, out);
}

// Round 4
// 371.490 us; speedup vs baseline: 1.7344x; 1.0609x over previous
//
#include <hip/hip_runtime.h>

#define TT 2048
#define BB 4
#define DD 1024
#define HH 16
#define HDIM 64
#define MM (TT*BB)   // 8192 rows, row index m = t*BB + b

typedef __attribute__((ext_vector_type(4))) float float4v;
typedef _Float16 half8 __attribute__((ext_vector_type(8)));
typedef _Float16 half4 __attribute__((ext_vector_type(4)));
typedef _Float16 half2v __attribute__((ext_vector_type(2)));

static __device__ __forceinline__ half4 pk4(float a, float b, float c, float d) {
    half2v h0 = __builtin_bit_cast(half2v, __builtin_amdgcn_cvt_pkrtz(a, b));
    half2v h1 = __builtin_bit_cast(half2v, __builtin_amdgcn_cvt_pkrtz(c, d));
    half4 hv; hv[0]=h0[0]; hv[1]=h0[1]; hv[2]=h1[0]; hv[3]=h1[1];
    return hv;
}

// guaranteed single-instruction 2^x (v_exp_f32)
static __device__ __forceinline__ float fexp2(float x) {
    float r; asm("v_exp_f32 %0, %1" : "=v"(r) : "v"(x)); return r;
}

// async global->LDS, 16B per lane; LDS dest wave-uniform base (+lane*16B)
#define GLD16(g, l) __builtin_amdgcn_global_load_lds( \
    (const __attribute__((address_space(1))) unsigned int*)(g), \
    (__attribute__((address_space(3))) unsigned int*)(l), 16, 0, 0)

// ---------------------------------------------------------------------------
// Kernel 0: fp32 -> fp16 convert of X (q,k,v) and W (Wq,Wk,Wv,Wo).
// ---------------------------------------------------------------------------
__global__ __launch_bounds__(256) void cvt_f16(
    const float* __restrict__ q, const float* __restrict__ k, const float* __restrict__ v,
    const float* __restrict__ wq, const float* __restrict__ wk, const float* __restrict__ wv,
    const float* __restrict__ wo,
    _Float16* __restrict__ qh, _Float16* __restrict__ kh, _Float16* __restrict__ vh,
    _Float16* __restrict__ wqh, _Float16* __restrict__ wkh, _Float16* __restrict__ wvh,
    _Float16* __restrict__ woh)
{
    const int z = blockIdx.z;
    const float* src; _Float16* dst; int n;
    switch (z) {
        case 0: src=q;  dst=qh;  n=MM*DD/8; break;
        case 1: src=k;  dst=kh;  n=MM*DD/8; break;
        case 2: src=v;  dst=vh;  n=MM*DD/8; break;
        case 3: src=wq; dst=wqh; n=DD*DD/8; break;
        case 4: src=wk; dst=wkh; n=DD*DD/8; break;
        case 5: src=wv; dst=wvh; n=DD*DD/8; break;
        default: src=wo; dst=woh; n=DD*DD/8; break;
    }
    for (int c = blockIdx.x*blockDim.x + threadIdx.x; c < n; c += gridDim.x*blockDim.x) {
        const float4v* s4 = (const float4v*)src + (size_t)c*2;
        float4v a = s4[0], b = s4[1];
        *(half4*)(dst + (size_t)c*8)     = pk4(a[0],a[1],a[2],a[3]);
        *(half4*)(dst + (size_t)c*8 + 4) = pk4(b[0],b[1],b[2],b[3]);
    }
}

// ---------------------------------------------------------------------------
// Kernel 1: QKV projection GEMM, 2-phase pipelined (attn-proven pattern):
// double-buffered LDS, next-tile global_load_lds issued BEFORE compute,
// ONE barrier per K-step, XOR-swizzled tiles (pre-swizzled global source,
// ^((lrow&7)<<3) on read) -> bank-conflict-free ds_read_b128.
// 1D grid, bijective XCD swizzle (1536 = 8*192). wqh/wkh/wvh contiguous ->
// single weight matrix of 3072 rows. Output scatter to (B,H,T,HD).
// ---------------------------------------------------------------------------
__global__ __launch_bounds__(256) void qkv_gemm(
    const _Float16* __restrict__ xq, const _Float16* __restrict__ xk, const _Float16* __restrict__ xv,
    const _Float16* __restrict__ wall,   // wqh base: 3072 x 1024
    const float* __restrict__ bq, const float* __restrict__ bk, const float* __restrict__ bv,
    _Float16* __restrict__ dq, _Float16* __restrict__ dk, _Float16* __restrict__ dv)
{
    __shared__ __attribute__((aligned(16))) _Float16 As[2][128*64];
    __shared__ __attribute__((aligned(16))) _Float16 Bs[2][128*64];

    // bijective XCD swizzle: 1536 blocks = 8 XCDs * 192
    const int id   = blockIdx.x;
    const int wgid = (id & 7)*192 + (id >> 3);
    const int z    = wgid / 512;          // 0..2 : q,k,v
    const int rem  = wgid & 511;
    const int by   = rem >> 3, bx = rem & 7;
    const int m0   = by*128, n0l = bx*128;          // n0l local in [0,1024)

    const _Float16* X = (z==0)?xq:((z==1)?xk:xv);
    const float* Bb   = (z==0)?bq:((z==1)?bk:bv);
    _Float16* Dst     = (z==0)?dq:((z==1)?dk:dv);
    const float osc   = (z==0) ? 0.18033688011112042f : 1.0f;  // (1/8)*log2(e)

    const int tid=threadIdx.x, lane=tid&63, w=tid>>6;
    const int wm=w>>1, wn=w&1;
    const int lrow=lane&15, lg=lane>>4;
    const int swzr = (lrow & 7) << 3;               // read-side XOR (halfs)

    // staging: wave w stages rows w*32+s*8+(lane>>3); source col pre-swizzled
    const int scol = ((lane&7) ^ (lane>>3))*8;      // halfs, within 64-half window
    const _Float16* ga = X    + (size_t)(m0 + w*32 + (lane>>3))*DD + scol;
    const _Float16* gb = wall + (size_t)(z*1024 + n0l + w*32 + (lane>>3))*DD + scol;

    float4v acc[4][4];
    for (int i=0;i<4;i++) for (int j=0;j<4;j++) acc[i][j]=(float4v){0.f,0.f,0.f,0.f};

    // prologue: stage K-step 0 into buffer 0
    #pragma unroll
    for (int s=0;s<4;s++) GLD16(ga + (size_t)s*8*DD, &As[0][(w*32+s*8)*64]);
    #pragma unroll
    for (int s=0;s<4;s++) GLD16(gb + (size_t)s*8*DD, &Bs[0][(w*32+s*8)*64]);
    __syncthreads();

    for (int t=0; t<16; t++) {
        const int cb = t & 1, nb = cb ^ 1;
        if (t < 15) {   // issue next tile's loads first; they land during compute
            const size_t k1 = (size_t)(t+1)*64;
            #pragma unroll
            for (int s=0;s<4;s++) GLD16(ga + (size_t)s*8*DD + k1, &As[nb][(w*32+s*8)*64]);
            #pragma unroll
            for (int s=0;s<4;s++) GLD16(gb + (size_t)s*8*DD + k1, &Bs[nb][(w*32+s*8)*64]);
        }
        #pragma unroll
        for (int kc=0;kc<2;kc++) {
            half8 a[4], b[4];
            #pragma unroll
            for (int i=0;i<4;i++) a[i] = *(const half8*)&As[cb][(wm*64+i*16+lrow)*64 + ((kc*32+lg*8) ^ swzr)];
            #pragma unroll
            for (int j=0;j<4;j++) b[j] = *(const half8*)&Bs[cb][(wn*64+j*16+lrow)*64 + ((kc*32+lg*8) ^ swzr)];
            #pragma unroll
            for (int i=0;i<4;i++)
            #pragma unroll
            for (int j=0;j<4;j++)
                acc[i][j] = __builtin_amdgcn_mfma_f32_16x16x32_f16(a[i], b[j], acc[i][j],0,0,0);
        }
        __syncthreads();   // cur reads done by all waves; next-tile loads drained
    }

    // epilogue: + bias, (Q only) exp2-scale, scatter to (B,H,T,HD)
    #pragma unroll
    for (int j=0;j<4;j++) {
        int n = n0l + wn*64 + j*16 + lrow;          // local n in [0,1024)
        float bias = Bb[n];
        int h = n >> 6, hd = n & 63;
        #pragma unroll
        for (int i=0;i<4;i++)
        #pragma unroll
        for (int r=0;r<4;r++) {
            int m = m0 + wm*64 + i*16 + lg*4 + r;
            int tt = m >> 2, b = m & 3;
            Dst[((size_t)(b*HH + h)*TT + tt)*HDIM + hd] = (_Float16)((acc[i][j][r] + bias)*osc);
        }
    }
}

// ---------------------------------------------------------------------------
// Kernel 1b: V (B,H,T,HD) -> V^T (B,H,HD,T). 4x4-cell register transpose.
// ---------------------------------------------------------------------------
__global__ __launch_bounds__(256) void v_transpose(
    const _Float16* __restrict__ Vb, _Float16* __restrict__ VbT)
{
    const int tile = blockIdx.x;            // t-tile 0..31
    const int bh   = blockIdx.y;            // 0..63
    const int tid = threadIdx.x, tg = tid & 15, hg = tid >> 4;
    const int t0 = tile*64;

    half4 rv[4];
    #pragma unroll
    for (int r=0;r<4;r++)
        rv[r] = *(const half4*)(Vb + ((size_t)bh*TT + t0 + tg*4 + r)*HDIM + hg*4);
    #pragma unroll
    for (int c=0;c<4;c++) {
        half4 tv; tv[0]=rv[0][c]; tv[1]=rv[1][c]; tv[2]=rv[2][c]; tv[3]=rv[3][c];
        *(half4*)(VbT + ((size_t)bh*HDIM + hg*4 + c)*TT + t0 + tg*4) = tv;
    }
}

// ---------------------------------------------------------------------------
// Kernel 2: flash-style attention, fp16, max-free softmax. (unchanged, 98us)
// Swapped QK^T, P in registers, x16 PV MFMA, LDS-staged K/V^T tiles
// (global_load_lds, double-buffered, 1 barrier/kt), both-sides XOR swizzle.
// ---------------------------------------------------------------------------
__global__ __launch_bounds__(256, 4) void attn(
    const _Float16* __restrict__ Qg, const _Float16* __restrict__ Kg,
    const _Float16* __restrict__ VT, _Float16* __restrict__ Ctx)
{
    __shared__ __attribute__((aligned(16))) _Float16 Kt[2][64*64];
    __shared__ __attribute__((aligned(16))) _Float16 Vs[2][64*64];

    const int id = blockIdx.x;
    const int bh = id & 63, qt = id >> 6;
    const int b = bh >> 4, h = bh & 15;
    const int tid = threadIdx.x, lane = tid & 63, w = tid >> 6;
    const int lrow = lane & 15, lg = lane >> 4;

    const _Float16* Qb  = Qg + ((size_t)bh*TT + qt*128)*HDIM;
    const _Float16* Kb  = Kg + (size_t)bh*TT*HDIM;      // [t][hd], rows 128B
    const _Float16* Vtb = VT + (size_t)bh*HDIM*TT;      // [hd][t], rows 4KB

    const int srow = w*16 + (lane>>3);                  // + s*8
    const int scol = ((lane&7) ^ (lane>>3))*8;          // halfs

    half8 qf[2][2];
    #pragma unroll
    for (int i=0;i<2;i++)
    #pragma unroll
    for (int kc=0;kc<2;kc++)
        qf[i][kc] = *(const half8*)(Qb + (size_t)(w*32 + i*16 + lrow)*HDIM + kc*32 + lg*8);

    float4v oacc[2][4];   // [i][jo]: O^T: hd = jo*16+lg*4+r, q = i*16+lrow
    for (int i=0;i<2;i++) for (int j=0;j<4;j++) oacc[i][j]=(float4v){0.f,0.f,0.f,0.f};
    float lsum[2] = {0.f, 0.f};

    #pragma unroll
    for (int s=0;s<2;s++) {
        GLD16(Kb  + (size_t)(srow + s*8)*HDIM + scol,        &Kt[0][(w*16 + s*8)*64]);
        GLD16(Vtb + (size_t)(srow + s*8)*TT   + scol,        &Vs[0][(w*16 + s*8)*64]);
    }
    __syncthreads();

    const int swz = (lrow & 7) << 3;   // read-side XOR (halfs)

    for (int kt = 0; kt < 32; kt++) {
        const int cb = kt & 1, nb = cb ^ 1;

        if (kt < 31) {
            #pragma unroll
            for (int s=0;s<2;s++) {
                GLD16(Kb  + (size_t)((kt+1)*64 + srow + s*8)*HDIM + scol, &Kt[nb][(w*16 + s*8)*64]);
                GLD16(Vtb + (size_t)(srow + s*8)*TT + (kt+1)*64 + scol,   &Vs[nb][(w*16 + s*8)*64]);
            }
        }

        // ---- S^T = K Q^T (swapped): st[j][i][r] = S[q=i*16+lrow][t=j*16+lg*4+r]
        float4v st[4][2];
        #pragma unroll
        for (int j=0;j<4;j++) for (int i=0;i<2;i++) st[j][i]=(float4v){0.f,0.f,0.f,0.f};
        #pragma unroll
        for (int kc=0;kc<2;kc++) {
            half8 kf[4];
            #pragma unroll
            for (int j=0;j<4;j++)
                kf[j] = *(const half8*)&Kt[cb][(j*16 + lrow)*64 + ((kc*32 + lg*8) ^ swz)];
            __builtin_amdgcn_s_setprio(1);
            #pragma unroll
            for (int j=0;j<4;j++)
            #pragma unroll
            for (int i=0;i<2;i++)
                st[j][i] = __builtin_amdgcn_mfma_f32_16x16x32_f16(kf[j], qf[i][kc], st[j][i],0,0,0);
            __builtin_amdgcn_s_setprio(0);
        }

        // ---- per-j: exp + pack + PV (K=16 MFMA, P stays in registers)
        #pragma unroll
        for (int j=0;j<4;j++) {
            half4 pa[2];
            #pragma unroll
            for (int i=0;i<2;i++) {
                float p0 = fexp2(st[j][i][0]);
                float p1 = fexp2(st[j][i][1]);
                float p2 = fexp2(st[j][i][2]);
                float p3 = fexp2(st[j][i][3]);
                lsum[i] += (p0+p1)+(p2+p3);
                pa[i] = pk4(p0,p1,p2,p3);
            }
            half4 vf[4];
            #pragma unroll
            for (int jo=0;jo<4;jo++)
                vf[jo] = *(const half4*)&Vs[cb][(jo*16 + lrow)*64 + ((j*16 + lg*4) ^ swz)];
            __builtin_amdgcn_s_setprio(1);
            #pragma unroll
            for (int i=0;i<2;i++)
            #pragma unroll
            for (int jo=0;jo<4;jo++)
                oacc[i][jo] = __builtin_amdgcn_mfma_f32_16x16x16f16(vf[jo], pa[i], oacc[i][jo],0,0,0);
            __builtin_amdgcn_s_setprio(0);
        }

        __syncthreads();
    }

    #pragma unroll
    for (int i=0;i<2;i++) {
        float s = lsum[i];
        s += __shfl_xor(s, 16, 64);
        s += __shfl_xor(s, 32, 64);
        lsum[i] = s;
    }

    #pragma unroll
    for (int i=0;i<2;i++) {
        float inv = 1.f / lsum[i];
        int t = qt*128 + w*32 + i*16 + lrow;
        _Float16* crow = Ctx + ((size_t)t*BB + b)*DD + h*HDIM;
        #pragma unroll
        for (int jo=0;jo<4;jo++) {
            *(half4*)(crow + jo*16 + lg*4) =
                pk4(oacc[i][jo][0]*inv, oacc[i][jo][1]*inv,
                    oacc[i][jo][2]*inv, oacc[i][jo][3]*inv);
        }
    }
}

// ---------------------------------------------------------------------------
// Kernel 3: out = (ctx @ Wo.T + bo) * time_decay, fp16 GEMM, fp32 out.
// Same 2-phase pipelined + swizzled structure as qkv_gemm. XCD swizzle 512=8*64.
// ---------------------------------------------------------------------------
__global__ __launch_bounds__(256) void out_gemm(
    const _Float16* __restrict__ Cx, const _Float16* __restrict__ Woh,
    const float* __restrict__ bo, const float* __restrict__ td,
    float* __restrict__ Out)
{
    __shared__ __attribute__((aligned(16))) _Float16 As[2][128*64];
    __shared__ __attribute__((aligned(16))) _Float16 Bs[2][128*64];

    const int id   = blockIdx.x;
    const int wgid = (id & 7)*64 + (id >> 3);
    const int by   = wgid >> 3, bx = wgid & 7;
    const int m0   = by*128, n0 = bx*128;

    const int tid=threadIdx.x, lane=tid&63, w=tid>>6;
    const int wm=w>>1, wn=w&1;
    const int lrow=lane&15, lg=lane>>4;
    const int swzr = (lrow & 7) << 3;

    const int scol = ((lane&7) ^ (lane>>3))*8;
    const _Float16* ga = Cx  + (size_t)(m0 + w*32 + (lane>>3))*DD + scol;
    const _Float16* gb = Woh + (size_t)(n0 + w*32 + (lane>>3))*DD + scol;

    float4v acc[4][4];
    for (int i=0;i<4;i++) for (int j=0;j<4;j++) acc[i][j]=(float4v){0.f,0.f,0.f,0.f};

    #pragma unroll
    for (int s=0;s<4;s++) GLD16(ga + (size_t)s*8*DD, &As[0][(w*32+s*8)*64]);
    #pragma unroll
    for (int s=0;s<4;s++) GLD16(gb + (size_t)s*8*DD, &Bs[0][(w*32+s*8)*64]);
    __syncthreads();

    for (int t=0; t<16; t++) {
        const int cb = t & 1, nb = cb ^ 1;
        if (t < 15) {
            const size_t k1 = (size_t)(t+1)*64;
            #pragma unroll
            for (int s=0;s<4;s++) GLD16(ga + (size_t)s*8*DD + k1, &As[nb][(w*32+s*8)*64]);
            #pragma unroll
            for (int s=0;s<4;s++) GLD16(gb + (size_t)s*8*DD + k1, &Bs[nb][(w*32+s*8)*64]);
        }
        #pragma unroll
        for (int kc=0;kc<2;kc++) {
            half8 a[4], b[4];
            #pragma unroll
            for (int i=0;i<4;i++) a[i] = *(const half8*)&As[cb][(wm*64+i*16+lrow)*64 + ((kc*32+lg*8) ^ swzr)];
            #pragma unroll
            for (int j=0;j<4;j++) b[j] = *(const half8*)&Bs[cb][(wn*64+j*16+lrow)*64 + ((kc*32+lg*8) ^ swzr)];
            #pragma unroll
            for (int i=0;i<4;i++)
            #pragma unroll
            for (int j=0;j<4;j++)
                acc[i][j] = __builtin_amdgcn_mfma_f32_16x16x32_f16(a[i], b[j], acc[i][j],0,0,0);
        }
        __syncthreads();
    }

    #pragma unroll
    for (int j=0;j<4;j++) {
        int n = n0 + wn*64 + j*16 + lrow;
        float bias = bo[n];
        #pragma unroll
        for (int i=0;i<4;i++)
        #pragma unroll
        for (int r=0;r<4;r++) {
            int m = m0 + wm*64 + i*16 + lg*4 + r;
            size_t off = (size_t)m*DD + n;
            Out[off] = (acc[i][j][r] + bias) * td[off];
        }
    }
}

// ---------------------------------------------------------------------------
extern "C" void kernel_launch(void* const* d_in, const int* in_sizes, int n_in,
                              void* d_out, int out_size, void* d_ws, size_t ws_size,
                              hipStream_t stream) {
    const float* q  = (const float*)d_in[0];
    const float* k  = (const float*)d_in[1];
    const float* v  = (const float*)d_in[2];
    const float* td = (const float*)d_in[3];
    const float* Wq = (const float*)d_in[4];
    const float* bq = (const float*)d_in[5];
    const float* Wk = (const float*)d_in[6];
    const float* bk = (const float*)d_in[7];
    const float* Wv = (const float*)d_in[8];
    const float* bv = (const float*)d_in[9];
    const float* Wo = (const float*)d_in[10];
    const float* bo = (const float*)d_in[11];
    float* out = (float*)d_out;

    // workspace (104 MB):
    //  [qh 16M][kh 16M][vh 16M][wqh 2M][wkh 2M][wvh 2M][woh 2M][Qb 16M][Kb 16M][Vb 16M]
    //  wqh/wkh/wvh contiguous -> fused 3072-row weight for qkv_gemm.
    //  VbT aliases vh (dead after qkv_gemm); Cx aliases qh (dead after qkv_gemm).
    _Float16* qh  = (_Float16*)d_ws;
    _Float16* kh  = qh  + (size_t)MM*DD;
    _Float16* vh  = kh  + (size_t)MM*DD;
    _Float16* wqh = vh  + (size_t)MM*DD;
    _Float16* wkh = wqh + (size_t)DD*DD;
    _Float16* wvh = wkh + (size_t)DD*DD;
    _Float16* woh = wvh + (size_t)DD*DD;
    _Float16* Qb  = woh + (size_t)DD*DD;
    _Float16* Kb  = Qb  + (size_t)MM*DD;
    _Float16* Vb  = Kb  + (size_t)MM*DD;
    _Float16* VbT = vh;   // alias: vh dead after qkv_gemm
    _Float16* Cx  = qh;   // alias: qh dead after qkv_gemm

    cvt_f16    <<<dim3(2048,1,7), 256, 0, stream>>>(q,k,v, Wq,Wk,Wv,Wo, qh,kh,vh, wqh,wkh,wvh,woh);
    qkv_gemm   <<<dim3(1536),     256, 0, stream>>>(qh,kh,vh, wqh, bq,bk,bv, Qb,Kb,Vb);
    v_transpose<<<dim3(32,64),    256, 0, stream>>>(Vb, VbT);
    attn       <<<dim3(1024),     256, 0, stream>>>(Qb, Kb, VbT, Cx);
    out_gemm   <<<dim3(512),      256, 0, stream>>>(Cx, woh, bo, td, out);
}